// Round 1
// baseline (1109.243 us; speedup 1.0000x reference)
//
#include <hip/hip_runtime.h>

#define INF_F __builtin_inff()

// ---------------------------------------------------------------------------
// kNN: one wave per target node. Per-lane register top-16, wave merge.
// Distance arithmetic matches the reference: contract off, separately rounded
// squares, sequential sum, tie-break by lower index.
// ---------------------------------------------------------------------------
__global__ __launch_bounds__(64) void knn_kernel(const float* __restrict__ loc,
                                                 int* __restrict__ knn, int n)
{
#pragma clang fp contract(off)
  const int i = blockIdx.x;
  const int lane = threadIdx.x;
  const float tx = loc[(size_t)i*4+0], ty = loc[(size_t)i*4+1];
  const float tz = loc[(size_t)i*4+2], tw = loc[(size_t)i*4+3];

  float d16[16]; int i16[16];
#pragma unroll
  for (int t = 0; t < 16; ++t) { d16[t] = INF_F; i16[t] = 0x7fffffff; }
  float worst = INF_F; int worsti = 0x7fffffff; int wslot = 0;

  for (int j0 = 0; j0 < n; j0 += 64) {
    const int j = j0 + lane;
    float d = INF_F;
    const bool valid = (j < n) && (j != i);
    if (valid) {
      const float4 p = *(const float4*)(loc + (size_t)j*4);
      const float a0 = p.x - tx, a1 = p.y - ty, a2 = p.z - tz, a3 = p.w - tw;
      const float s0 = a0*a0, s1 = a1*a1, s2 = a2*a2, s3 = a3*a3;
      d = ((s0 + s1) + s2) + s3;
    }
    const bool ins = valid && ((d < worst) || (d == worst && j < worsti));
    if (ins) {
#pragma unroll
      for (int t = 0; t < 16; ++t) if (t == wslot) { d16[t] = d; i16[t] = j; }
      worst = -INF_F; worsti = -1; wslot = 0;
#pragma unroll
      for (int t = 0; t < 16; ++t) {
        const bool b = (d16[t] > worst) || (d16[t] == worst && i16[t] > worsti);
        if (b) { worst = d16[t]; worsti = i16[t]; wslot = t; }
      }
    }
  }

  // merge: 16 rounds of wave argmin (tie -> lower index)
  for (int r = 0; r < 16; ++r) {
    float bd = INF_F; int bi = 0x7fffffff; int bs = 0;
#pragma unroll
    for (int t = 0; t < 16; ++t) {
      const bool b = (d16[t] < bd) || (d16[t] == bd && i16[t] < bi);
      if (b) { bd = d16[t]; bi = i16[t]; bs = t; }
    }
    float rd = bd; int ri = bi;
#pragma unroll
    for (int off = 32; off >= 1; off >>= 1) {
      const float od = __shfl_xor(rd, off, 64);
      const int   oi = __shfl_xor(ri, off, 64);
      if ((od < rd) || (od == rd && oi < ri)) { rd = od; ri = oi; }
    }
    if (lane == 0) knn[(size_t)i*16 + r] = ri;
    if (bi == ri) {
#pragma unroll
      for (int t = 0; t < 16; ++t) if (t == bs) { d16[t] = INF_F; i16[t] = 0x7fffffff; }
    }
  }
}

// ---------------------------------------------------------------------------
// CSR build for the static edge list (dst-grouped)
// ---------------------------------------------------------------------------
__global__ __launch_bounds__(256) void deg_kernel(const int* __restrict__ dst,
                                                  int* __restrict__ deg, int E)
{
  const int e = blockIdx.x * 256 + threadIdx.x;
  if (e < E) atomicAdd(&deg[dst[e]], 1);
}

__global__ __launch_bounds__(1024) void scan_kernel(const int* __restrict__ deg,
                                                    int* __restrict__ rowptr, int n)
{
  __shared__ int buf[1024];
  __shared__ int carry;
  if (threadIdx.x == 0) carry = 0;
  __syncthreads();
  for (int base = 0; base < n; base += 1024) {
    const int idx = base + threadIdx.x;
    const int v = (idx < n) ? deg[idx] : 0;
    buf[threadIdx.x] = v;
    __syncthreads();
    int sum = v;
    for (int off = 1; off < 1024; off <<= 1) {
      const int t = (threadIdx.x >= (unsigned)off) ? buf[threadIdx.x - off] : 0;
      __syncthreads();
      sum += t;
      buf[threadIdx.x] = sum;
      __syncthreads();
    }
    if (idx < n) rowptr[idx] = carry + sum - v;   // exclusive
    __syncthreads();
    if (threadIdx.x == 1023) carry += buf[1023];
    __syncthreads();
  }
  if (threadIdx.x == 0) rowptr[n] = carry;
}

__global__ __launch_bounds__(256) void scatter_kernel(const int* __restrict__ dst,
                                                      const int* __restrict__ rowptr,
                                                      int* __restrict__ fill,
                                                      int* __restrict__ csr, int E)
{
  const int e = blockIdx.x * 256 + threadIdx.x;
  if (e < E) {
    const int d = dst[e];
    const int pos = rowptr[d] + atomicAdd(&fill[d], 1);
    csr[pos] = e;
  }
}

// w1diff[o][i] = w1[o][i] - w1[o][64+i]   (o<128, i<64)
__global__ __launch_bounds__(256) void wdiff_kernel(const float* __restrict__ w1,
                                                    float* __restrict__ wd)
{
  const int idx = blockIdx.x * 256 + threadIdx.x;
  if (idx < 128 * 64) {
    const int o = idx >> 6, i = idx & 63;
    wd[idx] = w1[o*128 + i] - w1[o*128 + 64 + i];
  }
}

// ---------------------------------------------------------------------------
// Generic fp32 linear: C[M][cols] = act(A[M][K] @ W[cols][K]^T + bias)
// block = 256 threads (4 waves x 8 rows), tile 32 rows x 64 cols, K-step 64.
// ---------------------------------------------------------------------------
template<bool RELU, bool ACC>
__global__ __launch_bounds__(256) void linear_kernel(
    const float* __restrict__ A, int lda,
    const float* __restrict__ W, int ldw,
    const float* __restrict__ bias,
    float* __restrict__ C, int ldc, int M, int K)
{
  __shared__ float As[32 * 64];
  __shared__ float Ws[64 * 68];   // +4 pad: 8-way bank-group spread on row reads
  const int m0 = blockIdx.x * 32;
  const int c0 = blockIdx.y * 64;
  const int tid = threadIdx.x;
  const int wave = tid >> 6, lane = tid & 63;
  const int c = c0 + lane;

  float acc[8];
#pragma unroll
  for (int t = 0; t < 8; ++t) acc[t] = 0.f;

  for (int kt = 0; kt < K; kt += 64) {
    // stage A tile [32][64]
    {
      int idx = tid;
#pragma unroll
      for (int itr = 0; itr < 2; ++itr, idx += 256) {
        const int row = idx >> 4, col4 = idx & 15;
        const int gr = m0 + row;
        float4 v = make_float4(0.f, 0.f, 0.f, 0.f);
        if (gr < M) v = *(const float4*)(A + (size_t)gr*lda + kt + col4*4);
        *(float4*)(As + row*64 + col4*4) = v;
      }
      // stage W tile [64][64]
      idx = tid;
#pragma unroll
      for (int itr = 0; itr < 4; ++itr, idx += 256) {
        const int row = idx >> 4, col4 = idx & 15;
        const float4 v = *(const float4*)(W + (size_t)(c0 + row)*ldw + kt + col4*4);
        *(float4*)(Ws + row*68 + col4*4) = v;
      }
    }
    __syncthreads();
    const float* wr = Ws + lane*68;
    const float* ar = As + wave*8*64;
    for (int g = 0; g < 16; ++g) {
      const float4 w = *(const float4*)(wr + g*4);
#pragma unroll
      for (int t = 0; t < 8; ++t) {
        const float4 a = *(const float4*)(ar + t*64 + g*4);
        acc[t] = fmaf(w.x, a.x, fmaf(w.y, a.y, fmaf(w.z, a.z, fmaf(w.w, a.w, acc[t]))));
      }
    }
    __syncthreads();
  }

  const float b = bias ? bias[c] : 0.f;
#pragma unroll
  for (int t = 0; t < 8; ++t) {
    const int gr = m0 + wave*8 + t;
    if (gr < M) {
      float v = acc[t] + b;
      if (RELU) v = fmaxf(v, 0.f);
      float* cp = C + (size_t)gr*ldc + c;
      if (ACC) v += *cp;
      *cp = v;
    }
  }
}

// ---------------------------------------------------------------------------
// Static conv message + segment max. 4 waves/block, one dst node per wave,
// lane = output channel. agg[d][c] = max(0, max_e relu-arg)  (relu folded).
// ---------------------------------------------------------------------------
__global__ __launch_bounds__(256) void static_msg_kernel(
    const float* __restrict__ R, const float* __restrict__ ea,
    const float* __restrict__ wm, const float* __restrict__ bm,
    const int* __restrict__ srcs, const int* __restrict__ csr,
    const int* __restrict__ rowptr, float* __restrict__ agg, int n)
{
  __shared__ float wma[64][17];   // cols 0..15 of wm, padded
  for (int idx = threadIdx.x; idx < 1024; idx += 256) {
    const int r = idx >> 4, cc = idx & 15;
    wma[r][cc] = wm[r*80 + cc];
  }
  __syncthreads();
  const int wave = threadIdx.x >> 6, lane = threadIdx.x & 63;
  const int d = blockIdx.x * 4 + wave;
  if (d >= n) return;
  const int beg = rowptr[d], end = rowptr[d+1];
  const float base = bm[lane] - R[(size_t)d*64 + lane];
  const float* wr = wma[lane];
  float vmax = 0.f;
  for (int p = beg; p < end; ++p) {
    const int e = csr[p];
    const int s = srcs[e];
    float acc = base + R[(size_t)s*64 + lane];
    const float4* e4 = (const float4*)(ea + (size_t)e*16);
    const float4 q0 = e4[0], q1 = e4[1], q2 = e4[2], q3 = e4[3];
    float ev[16];
    ev[0]=q0.x; ev[1]=q0.y; ev[2]=q0.z; ev[3]=q0.w;
    ev[4]=q1.x; ev[5]=q1.y; ev[6]=q1.z; ev[7]=q1.w;
    ev[8]=q2.x; ev[9]=q2.y; ev[10]=q2.z; ev[11]=q2.w;
    ev[12]=q3.x; ev[13]=q3.y; ev[14]=q3.z; ev[15]=q3.w;
#pragma unroll
    for (int dd = 0; dd < 16; ++dd) acc = fmaf(ev[dd], wr[dd], acc);
    vmax = fmaxf(vmax, acc);    // == max(vmax, relu(acc)) since vmax >= 0
  }
  agg[(size_t)d*64 + lane] = vmax;
}

// ---------------------------------------------------------------------------
// Dynamic conv: per target i, 17 neighbors (16 kNN + self).
// t_e = relu(P[i] + Q[j]); out[i][c] = relu(max_e (t_e . W2[c]) + b2[c]).
// 4 waves/block (one target each); W2 staged once in padded LDS; per-wave T.
// ---------------------------------------------------------------------------
template<int NB>
__device__ __forceinline__ float dyn_block(
    int i, int nb0, const int* __restrict__ knn,
    const float* __restrict__ P, const float* __restrict__ Q,
    const float* __restrict__ w2row, float* __restrict__ Tw,
    int lane, float vmax)
{
  for (int idx = lane; idx < NB * 32; idx += 64) {
    const int off = idx << 2;
    const int nb = off >> 7, kk = off & 127;
    const int nbg = nb0 + nb;
    const int j = (nbg < 16) ? knn[(size_t)i*16 + nbg] : i;
    const float4 p = *(const float4*)(P + (size_t)i*128 + kk);
    const float4 q = *(const float4*)(Q + (size_t)j*128 + kk);
    float4 t;
    t.x = fmaxf(p.x + q.x, 0.f); t.y = fmaxf(p.y + q.y, 0.f);
    t.z = fmaxf(p.z + q.z, 0.f); t.w = fmaxf(p.w + q.w, 0.f);
    *(float4*)(Tw + off) = t;
  }
  __syncthreads();
  float acc[NB];
#pragma unroll
  for (int t = 0; t < NB; ++t) acc[t] = 0.f;
  for (int g = 0; g < 32; ++g) {
    const float4 w = *(const float4*)(w2row + g*4);
#pragma unroll
    for (int t = 0; t < NB; ++t) {
      const float4 tv = *(const float4*)(Tw + t*128 + g*4);
      acc[t] = fmaf(w.x, tv.x, fmaf(w.y, tv.y, fmaf(w.z, tv.z, fmaf(w.w, tv.w, acc[t]))));
    }
  }
#pragma unroll
  for (int t = 0; t < NB; ++t) vmax = fmaxf(vmax, acc[t]);
  return vmax;
}

__global__ __launch_bounds__(256) void dyn_conv_kernel(
    const float* __restrict__ P, const float* __restrict__ Q,
    const float* __restrict__ W2, const float* __restrict__ b2,
    const int* __restrict__ knn, float* __restrict__ out, int ldo, int n)
{
  __shared__ float w2s[64 * 132];   // [64][128] padded to 132
  __shared__ float T[4][1152];      // per-wave [9][128]
  for (int idx = threadIdx.x; idx < 2048; idx += 256) {
    const int r = idx >> 5, g = idx & 31;
    *(float4*)(&w2s[r*132 + g*4]) = *(const float4*)(W2 + r*128 + g*4);
  }
  __syncthreads();
  const int wave = threadIdx.x >> 6, lane = threadIdx.x & 63;
  const int i = blockIdx.x * 4 + wave;
  float vmax = -INF_F;
  vmax = dyn_block<9>(i, 0, knn, P, Q, &w2s[lane*132], T[wave], lane, vmax);
  vmax = dyn_block<8>(i, 9, knn, P, Q, &w2s[lane*132], T[wave], lane, vmax);
  if (i < n) out[(size_t)i*ldo + lane] = fmaxf(vmax + b2[lane], 0.f);
}

// ---------------------------------------------------------------------------
// Host orchestration
// ---------------------------------------------------------------------------
extern "C" void kernel_launch(void* const* d_in, const int* in_sizes, int n_in,
                              void* d_out, int out_size, void* d_ws, size_t ws_size,
                              hipStream_t stream)
{
  const float* x   = (const float*)d_in[0];
  const int*   ei  = (const int*)d_in[1];
  const float* ea  = (const float*)d_in[2];
  const float* loc = (const float*)d_in[3];
  const float* sg_wm[3] = {(const float*)d_in[5],  (const float*)d_in[9],  (const float*)d_in[13]};
  const float* sg_bm[3] = {(const float*)d_in[6],  (const float*)d_in[10], (const float*)d_in[14]};
  const float* sg_wu[3] = {(const float*)d_in[7],  (const float*)d_in[11], (const float*)d_in[15]};
  const float* sg_bu[3] = {(const float*)d_in[8],  (const float*)d_in[12], (const float*)d_in[16]};
  const float* dg_w1[2] = {(const float*)d_in[17], (const float*)d_in[21]};
  const float* dg_b1[2] = {(const float*)d_in[18], (const float*)d_in[22]};
  const float* dg_w2[2] = {(const float*)d_in[19], (const float*)d_in[23]};
  const float* dg_b2[2] = {(const float*)d_in[20], (const float*)d_in[24]};
  const float* f1_w = (const float*)d_in[25];
  const float* f1_b = (const float*)d_in[26];
  const float* f2_w = (const float*)d_in[27];
  const float* f2_b = (const float*)d_in[28];
  float* out = (float*)d_out;

  const int n    = in_sizes[0] / 64;
  const int Etot = in_sizes[1] / 2;
  const int* srcp = ei;
  const int* dstp = ei + Etot;

  char* basep = (char*)d_ws;
  size_t cur = 0;
  auto alloc = [&](size_t bytes) -> void* {
    void* p = basep + cur;
    cur = (cur + bytes + 255) & ~(size_t)255;
    return p;
  };
  float* CAT  = (float*)alloc((size_t)n * 320 * 4);
  float* Rb   = (float*)alloc((size_t)n * 64 * 4);
  float* Pb   = (float*)alloc((size_t)n * 128 * 4);
  float* Qb   = (float*)alloc((size_t)n * 128 * 4);
  float* aggb = (float*)alloc((size_t)n * 64 * 4);
  float* fu1  = (float*)alloc((size_t)n * 64 * 4);
  float* w1d[2];
  w1d[0] = (float*)alloc(128 * 64 * 4);
  w1d[1] = (float*)alloc(128 * 64 * 4);
  int* knnb   = (int*)alloc((size_t)n * 16 * 4);
  int* deg    = (int*)alloc((size_t)2 * n * 4);   // deg + fill, contiguous
  int* fill   = deg + n;
  int* rowptr = (int*)alloc((size_t)(n + 1) * 4);
  int* csr    = (int*)alloc((size_t)Etot * 4);
  (void)ws_size; (void)n_in; (void)out_size;

  hipMemsetAsync(deg, 0, (size_t)2 * n * 4, stream);
  knn_kernel<<<n, 64, 0, stream>>>(loc, knnb, n);
  deg_kernel<<<(Etot + 255) / 256, 256, 0, stream>>>(dstp, deg, Etot);
  scan_kernel<<<1, 1024, 0, stream>>>(deg, rowptr, n);
  scatter_kernel<<<(Etot + 255) / 256, 256, 0, stream>>>(dstp, rowptr, fill, csr, Etot);
  wdiff_kernel<<<(128 * 64 + 255) / 256, 256, 0, stream>>>(dg_w1[0], w1d[0]);
  wdiff_kernel<<<(128 * 64 + 255) / 256, 256, 0, stream>>>(dg_w1[1], w1d[1]);

  const int mb = (n + 31) / 32;
  auto lin = [&](const float* A, int lda, const float* W, int ldw, const float* bias,
                 float* C, int ldc, int K, int ncols, bool relu, bool accum) {
    dim3 grid(mb, ncols / 64);
    if (relu)       linear_kernel<true,  false><<<grid, 256, 0, stream>>>(A, lda, W, ldw, bias, C, ldc, n, K);
    else if (accum) linear_kernel<false, true ><<<grid, 256, 0, stream>>>(A, lda, W, ldw, bias, C, ldc, n, K);
    else            linear_kernel<false, false><<<grid, 256, 0, stream>>>(A, lda, W, ldw, bias, C, ldc, n, K);
  };

  // static layers: x -> h1(CAT+0) -> h2(CAT+192) -> h3(CAT+256)
  const float* hin = x; int hlda = 64;
  float* hout[3] = {CAT + 0, CAT + 192, CAT + 256};
  for (int l = 0; l < 3; ++l) {
    lin(hin, hlda, sg_wm[l] + 16, 80, nullptr, Rb, 64, 64, 64, false, false);
    static_msg_kernel<<<(n + 3) / 4, 256, 0, stream>>>(Rb, ea, sg_wm[l], sg_bm[l],
                                                       srcp, csr, rowptr, aggb, n);
    lin(aggb, 64, sg_wu[l], 64, sg_bu[l], hout[l], 320, 64, 64, true, false);
    hin = hout[l]; hlda = 320;
  }

  // dynamic layers: h1 -> g1(CAT+64); g1 -> g2(CAT+128)
  const float* din[2] = {CAT + 0, CAT + 64};
  float* doutp[2] = {CAT + 64, CAT + 128};
  for (int l = 0; l < 2; ++l) {
    lin(din[l], 320, w1d[l], 64, dg_b1[l], Pb, 128, 64, 128, false, false);
    lin(din[l], 320, dg_w1[l] + 64, 128, nullptr, Qb, 128, 64, 128, false, false);
    dyn_conv_kernel<<<(n + 3) / 4, 256, 0, stream>>>(Pb, Qb, dg_w2[l], dg_b2[l],
                                                     knnb, doutp[l], 320, n);
  }

  // fusion
  lin(CAT, 320, f1_w, 320, f1_b, fu1, 64, 320, 64, true,  false);
  lin(CAT, 320, f2_w + 64, 384, f2_b, out, 64, 320, 64, false, false);
  lin(fu1, 64, f2_w, 384, nullptr, out, 64, 64, 64, false, true);
}

// Round 2
// 685.420 us; speedup vs baseline: 1.6183x; 1.6183x over previous
//
#include <hip/hip_runtime.h>

#define INF_F __builtin_inff()

// ---------------------------------------------------------------------------
// kNN, threshold-scan formulation. One wave per target node, 4 waves/block.
// Key = (dist_bits << 32) | j  — u64 ascending == (dist, index) lexicographic,
// exactly the reference top_k ordering (dist >= 0 so float bits monotonic).
// Survivors (key < tau) are compact-appended to a per-wave LDS buffer; a
// 16-round wave-argmin "refine" runs when the buffer fills and once at the
// end. Only the SET of 16 neighbors matters downstream (segment-max).
// Distance arithmetic matches the reference bit-for-bit: contract off,
// separately rounded squares, sequential sum.
// ---------------------------------------------------------------------------
__device__ __forceinline__ unsigned long long
knn_refine(unsigned long long* __restrict__ B, int cnt, int lane,
           unsigned long long& topsave)
{
  unsigned long long v[4];
#pragma unroll
  for (int t = 0; t < 4; ++t) {
    const int idx = lane + 64 * t;
    v[t] = (idx < cnt) ? B[idx] : ~0ull;
  }
  unsigned long long tau = ~0ull;
#pragma unroll
  for (int r = 0; r < 16; ++r) {
    // lane-local min of up to 4 keys
    unsigned long long m = v[0]; int s = 0;
#pragma unroll
    for (int t = 1; t < 4; ++t) if (v[t] < m) { m = v[t]; s = t; }
    // wave butterfly min (keys unique -> exactly one owner)
    unsigned long long mm = m;
#pragma unroll
    for (int off = 32; off >= 1; off >>= 1) {
      const unsigned long long o = __shfl_xor(mm, off, 64);
      if (o < mm) mm = o;
    }
    const bool killer = (m == mm);
#pragma unroll
    for (int t = 0; t < 4; ++t) if (killer && s == t) v[t] = ~0ull;
    if (lane == r) topsave = mm;
    if (r == 15) tau = mm;
  }
  // compact the winners back to the buffer front (caller resets cnt=16)
  if (lane < 16) B[lane] = topsave;
  return tau;
}

__global__ __launch_bounds__(256) void knn_kernel(const float* __restrict__ loc,
                                                  int* __restrict__ knn, int n)
{
#pragma clang fp contract(off)
  constexpr int CAP = 256;
  constexpr int TRIG = CAP - 64;
  __shared__ unsigned long long Bs[4][CAP];
  const int wave = threadIdx.x >> 6, lane = threadIdx.x & 63;
  const int i = blockIdx.x * 4 + wave;
  if (i >= n) return;
  unsigned long long* B = Bs[wave];

  const float tx = loc[(size_t)i*4+0], ty = loc[(size_t)i*4+1];
  const float tz = loc[(size_t)i*4+2], tw = loc[(size_t)i*4+3];

  unsigned long long tau = ~0ull;   // current 16th-best key (wave-uniform)
  unsigned long long topsave = ~0ull;
  int cnt = 0;

  for (int j0 = 0; j0 < n; j0 += 64) {
    const int j = j0 + lane;
    unsigned long long key = ~0ull;
    if (j < n && j != i) {
      const float4 p = *(const float4*)(loc + (size_t)j*4);
      const float a0 = p.x - tx, a1 = p.y - ty, a2 = p.z - tz, a3 = p.w - tw;
      const float s0 = a0*a0, s1 = a1*a1, s2 = a2*a2, s3 = a3*a3;
      const float d = ((s0 + s1) + s2) + s3;
      key = ((unsigned long long)__float_as_uint(d) << 32) | (unsigned)j;
    }
    const bool surv = key < tau;
    const unsigned long long mask = __ballot(surv);
    if (mask) {
      const unsigned pre = __builtin_amdgcn_mbcnt_hi(
          (unsigned)(mask >> 32),
          __builtin_amdgcn_mbcnt_lo((unsigned)mask, 0u));
      if (surv) B[cnt + pre] = key;
      cnt += (int)__popcll(mask);
      if (cnt > TRIG) {
        tau = knn_refine(B, cnt, lane, topsave);
        cnt = 16;
      }
    }
  }
  if (cnt > 16) (void)knn_refine(B, cnt, lane, topsave);
  if (lane < 16) knn[(size_t)i*16 + lane] = (int)(topsave & 0xFFFFFFFFull);
}

// ---------------------------------------------------------------------------
// CSR build for the static edge list (dst-grouped)
// ---------------------------------------------------------------------------
__global__ __launch_bounds__(256) void deg_kernel(const int* __restrict__ dst,
                                                  int* __restrict__ deg, int E)
{
  const int e = blockIdx.x * 256 + threadIdx.x;
  if (e < E) atomicAdd(&deg[dst[e]], 1);
}

__global__ __launch_bounds__(1024) void scan_kernel(const int* __restrict__ deg,
                                                    int* __restrict__ rowptr, int n)
{
  __shared__ int buf[1024];
  __shared__ int carry;
  if (threadIdx.x == 0) carry = 0;
  __syncthreads();
  for (int base = 0; base < n; base += 1024) {
    const int idx = base + threadIdx.x;
    const int v = (idx < n) ? deg[idx] : 0;
    buf[threadIdx.x] = v;
    __syncthreads();
    int sum = v;
    for (int off = 1; off < 1024; off <<= 1) {
      const int t = (threadIdx.x >= (unsigned)off) ? buf[threadIdx.x - off] : 0;
      __syncthreads();
      sum += t;
      buf[threadIdx.x] = sum;
      __syncthreads();
    }
    if (idx < n) rowptr[idx] = carry + sum - v;   // exclusive
    __syncthreads();
    if (threadIdx.x == 1023) carry += buf[1023];
    __syncthreads();
  }
  if (threadIdx.x == 0) rowptr[n] = carry;
}

__global__ __launch_bounds__(256) void scatter_kernel(const int* __restrict__ dst,
                                                      const int* __restrict__ rowptr,
                                                      int* __restrict__ fill,
                                                      int* __restrict__ csr, int E)
{
  const int e = blockIdx.x * 256 + threadIdx.x;
  if (e < E) {
    const int d = dst[e];
    const int pos = rowptr[d] + atomicAdd(&fill[d], 1);
    csr[pos] = e;
  }
}

// w1diff[o][i] = w1[o][i] - w1[o][64+i]   (o<128, i<64)
__global__ __launch_bounds__(256) void wdiff_kernel(const float* __restrict__ w1,
                                                    float* __restrict__ wd)
{
  const int idx = blockIdx.x * 256 + threadIdx.x;
  if (idx < 128 * 64) {
    const int o = idx >> 6, i = idx & 63;
    wd[idx] = w1[o*128 + i] - w1[o*128 + 64 + i];
  }
}

// ---------------------------------------------------------------------------
// Generic fp32 linear: C[M][cols] = act(A[M][K] @ W[cols][K]^T + bias)
// block = 256 threads (4 waves x 8 rows), tile 32 rows x 64 cols, K-step 64.
// ---------------------------------------------------------------------------
template<bool RELU, bool ACC>
__global__ __launch_bounds__(256) void linear_kernel(
    const float* __restrict__ A, int lda,
    const float* __restrict__ W, int ldw,
    const float* __restrict__ bias,
    float* __restrict__ C, int ldc, int M, int K)
{
  __shared__ float As[32 * 64];
  __shared__ float Ws[64 * 68];   // +4 pad: 8-way bank-group spread on row reads
  const int m0 = blockIdx.x * 32;
  const int c0 = blockIdx.y * 64;
  const int tid = threadIdx.x;
  const int wave = tid >> 6, lane = tid & 63;
  const int c = c0 + lane;

  float acc[8];
#pragma unroll
  for (int t = 0; t < 8; ++t) acc[t] = 0.f;

  for (int kt = 0; kt < K; kt += 64) {
    // stage A tile [32][64]
    {
      int idx = tid;
#pragma unroll
      for (int itr = 0; itr < 2; ++itr, idx += 256) {
        const int row = idx >> 4, col4 = idx & 15;
        const int gr = m0 + row;
        float4 v = make_float4(0.f, 0.f, 0.f, 0.f);
        if (gr < M) v = *(const float4*)(A + (size_t)gr*lda + kt + col4*4);
        *(float4*)(As + row*64 + col4*4) = v;
      }
      // stage W tile [64][64]
      idx = tid;
#pragma unroll
      for (int itr = 0; itr < 4; ++itr, idx += 256) {
        const int row = idx >> 4, col4 = idx & 15;
        const float4 v = *(const float4*)(W + (size_t)(c0 + row)*ldw + kt + col4*4);
        *(float4*)(Ws + row*68 + col4*4) = v;
      }
    }
    __syncthreads();
    const float* wr = Ws + lane*68;
    const float* ar = As + wave*8*64;
    for (int g = 0; g < 16; ++g) {
      const float4 w = *(const float4*)(wr + g*4);
#pragma unroll
      for (int t = 0; t < 8; ++t) {
        const float4 a = *(const float4*)(ar + t*64 + g*4);
        acc[t] = fmaf(w.x, a.x, fmaf(w.y, a.y, fmaf(w.z, a.z, fmaf(w.w, a.w, acc[t]))));
      }
    }
    __syncthreads();
  }

  const float b = bias ? bias[c] : 0.f;
#pragma unroll
  for (int t = 0; t < 8; ++t) {
    const int gr = m0 + wave*8 + t;
    if (gr < M) {
      float v = acc[t] + b;
      if (RELU) v = fmaxf(v, 0.f);
      float* cp = C + (size_t)gr*ldc + c;
      if (ACC) v += *cp;
      *cp = v;
    }
  }
}

// ---------------------------------------------------------------------------
// Static conv message + segment max. 4 waves/block, one dst node per wave,
// lane = output channel. agg[d][c] = max(0, max_e relu-arg)  (relu folded).
// ---------------------------------------------------------------------------
__global__ __launch_bounds__(256) void static_msg_kernel(
    const float* __restrict__ R, const float* __restrict__ ea,
    const float* __restrict__ wm, const float* __restrict__ bm,
    const int* __restrict__ srcs, const int* __restrict__ csr,
    const int* __restrict__ rowptr, float* __restrict__ agg, int n)
{
  __shared__ float wma[64][17];   // cols 0..15 of wm, padded
  for (int idx = threadIdx.x; idx < 1024; idx += 256) {
    const int r = idx >> 4, cc = idx & 15;
    wma[r][cc] = wm[r*80 + cc];
  }
  __syncthreads();
  const int wave = threadIdx.x >> 6, lane = threadIdx.x & 63;
  const int d = blockIdx.x * 4 + wave;
  if (d >= n) return;
  const int beg = rowptr[d], end = rowptr[d+1];
  const float base = bm[lane] - R[(size_t)d*64 + lane];
  const float* wr = wma[lane];
  float vmax = 0.f;
  for (int p = beg; p < end; ++p) {
    const int e = csr[p];
    const int s = srcs[e];
    float acc = base + R[(size_t)s*64 + lane];
    const float4* e4 = (const float4*)(ea + (size_t)e*16);
    const float4 q0 = e4[0], q1 = e4[1], q2 = e4[2], q3 = e4[3];
    float ev[16];
    ev[0]=q0.x; ev[1]=q0.y; ev[2]=q0.z; ev[3]=q0.w;
    ev[4]=q1.x; ev[5]=q1.y; ev[6]=q1.z; ev[7]=q1.w;
    ev[8]=q2.x; ev[9]=q2.y; ev[10]=q2.z; ev[11]=q2.w;
    ev[12]=q3.x; ev[13]=q3.y; ev[14]=q3.z; ev[15]=q3.w;
#pragma unroll
    for (int dd = 0; dd < 16; ++dd) acc = fmaf(ev[dd], wr[dd], acc);
    vmax = fmaxf(vmax, acc);    // == max(vmax, relu(acc)) since vmax >= 0
  }
  agg[(size_t)d*64 + lane] = vmax;
}

// ---------------------------------------------------------------------------
// Dynamic conv: per target i, 17 neighbors (16 kNN + self).
// t_e = relu(P[i] + Q[j]); out[i][c] = relu(max_e (t_e . W2[c]) + b2[c]).
// 4 waves/block (one target each); W2 staged once in padded LDS; per-wave T.
// ---------------------------------------------------------------------------
template<int NB>
__device__ __forceinline__ float dyn_block(
    int i, int nb0, const int* __restrict__ knn,
    const float* __restrict__ P, const float* __restrict__ Q,
    const float* __restrict__ w2row, float* __restrict__ Tw,
    int lane, float vmax)
{
  for (int idx = lane; idx < NB * 32; idx += 64) {
    const int off = idx << 2;
    const int nb = off >> 7, kk = off & 127;
    const int nbg = nb0 + nb;
    const int j = (nbg < 16) ? knn[(size_t)i*16 + nbg] : i;
    const float4 p = *(const float4*)(P + (size_t)i*128 + kk);
    const float4 q = *(const float4*)(Q + (size_t)j*128 + kk);
    float4 t;
    t.x = fmaxf(p.x + q.x, 0.f); t.y = fmaxf(p.y + q.y, 0.f);
    t.z = fmaxf(p.z + q.z, 0.f); t.w = fmaxf(p.w + q.w, 0.f);
    *(float4*)(Tw + off) = t;
  }
  __syncthreads();
  float acc[NB];
#pragma unroll
  for (int t = 0; t < NB; ++t) acc[t] = 0.f;
  for (int g = 0; g < 32; ++g) {
    const float4 w = *(const float4*)(w2row + g*4);
#pragma unroll
    for (int t = 0; t < NB; ++t) {
      const float4 tv = *(const float4*)(Tw + t*128 + g*4);
      acc[t] = fmaf(w.x, tv.x, fmaf(w.y, tv.y, fmaf(w.z, tv.z, fmaf(w.w, tv.w, acc[t]))));
    }
  }
#pragma unroll
  for (int t = 0; t < NB; ++t) vmax = fmaxf(vmax, acc[t]);
  return vmax;
}

__global__ __launch_bounds__(256) void dyn_conv_kernel(
    const float* __restrict__ P, const float* __restrict__ Q,
    const float* __restrict__ W2, const float* __restrict__ b2,
    const int* __restrict__ knn, float* __restrict__ out, int ldo, int n)
{
  __shared__ float w2s[64 * 132];   // [64][128] padded to 132
  __shared__ float T[4][1152];      // per-wave [9][128]
  for (int idx = threadIdx.x; idx < 2048; idx += 256) {
    const int r = idx >> 5, g = idx & 31;
    *(float4*)(&w2s[r*132 + g*4]) = *(const float4*)(W2 + r*128 + g*4);
  }
  __syncthreads();
  const int wave = threadIdx.x >> 6, lane = threadIdx.x & 63;
  const int i = blockIdx.x * 4 + wave;
  float vmax = -INF_F;
  vmax = dyn_block<9>(i, 0, knn, P, Q, &w2s[lane*132], T[wave], lane, vmax);
  vmax = dyn_block<8>(i, 9, knn, P, Q, &w2s[lane*132], T[wave], lane, vmax);
  if (i < n) out[(size_t)i*ldo + lane] = fmaxf(vmax + b2[lane], 0.f);
}

// ---------------------------------------------------------------------------
// Host orchestration
// ---------------------------------------------------------------------------
extern "C" void kernel_launch(void* const* d_in, const int* in_sizes, int n_in,
                              void* d_out, int out_size, void* d_ws, size_t ws_size,
                              hipStream_t stream)
{
  const float* x   = (const float*)d_in[0];
  const int*   ei  = (const int*)d_in[1];
  const float* ea  = (const float*)d_in[2];
  const float* loc = (const float*)d_in[3];
  const float* sg_wm[3] = {(const float*)d_in[5],  (const float*)d_in[9],  (const float*)d_in[13]};
  const float* sg_bm[3] = {(const float*)d_in[6],  (const float*)d_in[10], (const float*)d_in[14]};
  const float* sg_wu[3] = {(const float*)d_in[7],  (const float*)d_in[11], (const float*)d_in[15]};
  const float* sg_bu[3] = {(const float*)d_in[8],  (const float*)d_in[12], (const float*)d_in[16]};
  const float* dg_w1[2] = {(const float*)d_in[17], (const float*)d_in[21]};
  const float* dg_b1[2] = {(const float*)d_in[18], (const float*)d_in[22]};
  const float* dg_w2[2] = {(const float*)d_in[19], (const float*)d_in[23]};
  const float* dg_b2[2] = {(const float*)d_in[20], (const float*)d_in[24]};
  const float* f1_w = (const float*)d_in[25];
  const float* f1_b = (const float*)d_in[26];
  const float* f2_w = (const float*)d_in[27];
  const float* f2_b = (const float*)d_in[28];
  float* out = (float*)d_out;

  const int n    = in_sizes[0] / 64;
  const int Etot = in_sizes[1] / 2;
  const int* srcp = ei;
  const int* dstp = ei + Etot;

  char* basep = (char*)d_ws;
  size_t cur = 0;
  auto alloc = [&](size_t bytes) -> void* {
    void* p = basep + cur;
    cur = (cur + bytes + 255) & ~(size_t)255;
    return p;
  };
  float* CAT  = (float*)alloc((size_t)n * 320 * 4);
  float* Rb   = (float*)alloc((size_t)n * 64 * 4);
  float* Pb   = (float*)alloc((size_t)n * 128 * 4);
  float* Qb   = (float*)alloc((size_t)n * 128 * 4);
  float* aggb = (float*)alloc((size_t)n * 64 * 4);
  float* fu1  = (float*)alloc((size_t)n * 64 * 4);
  float* w1d[2];
  w1d[0] = (float*)alloc(128 * 64 * 4);
  w1d[1] = (float*)alloc(128 * 64 * 4);
  int* knnb   = (int*)alloc((size_t)n * 16 * 4);
  int* deg    = (int*)alloc((size_t)2 * n * 4);   // deg + fill, contiguous
  int* fill   = deg + n;
  int* rowptr = (int*)alloc((size_t)(n + 1) * 4);
  int* csr    = (int*)alloc((size_t)Etot * 4);
  (void)ws_size; (void)n_in; (void)out_size;

  hipMemsetAsync(deg, 0, (size_t)2 * n * 4, stream);
  knn_kernel<<<(n + 3) / 4, 256, 0, stream>>>(loc, knnb, n);
  deg_kernel<<<(Etot + 255) / 256, 256, 0, stream>>>(dstp, deg, Etot);
  scan_kernel<<<1, 1024, 0, stream>>>(deg, rowptr, n);
  scatter_kernel<<<(Etot + 255) / 256, 256, 0, stream>>>(dstp, rowptr, fill, csr, Etot);
  wdiff_kernel<<<(128 * 64 + 255) / 256, 256, 0, stream>>>(dg_w1[0], w1d[0]);
  wdiff_kernel<<<(128 * 64 + 255) / 256, 256, 0, stream>>>(dg_w1[1], w1d[1]);

  const int mb = (n + 31) / 32;
  auto lin = [&](const float* A, int lda, const float* W, int ldw, const float* bias,
                 float* C, int ldc, int K, int ncols, bool relu, bool accum) {
    dim3 grid(mb, ncols / 64);
    if (relu)       linear_kernel<true,  false><<<grid, 256, 0, stream>>>(A, lda, W, ldw, bias, C, ldc, n, K);
    else if (accum) linear_kernel<false, true ><<<grid, 256, 0, stream>>>(A, lda, W, ldw, bias, C, ldc, n, K);
    else            linear_kernel<false, false><<<grid, 256, 0, stream>>>(A, lda, W, ldw, bias, C, ldc, n, K);
  };

  // static layers: x -> h1(CAT+0) -> h2(CAT+192) -> h3(CAT+256)
  const float* hin = x; int hlda = 64;
  float* hout[3] = {CAT + 0, CAT + 192, CAT + 256};
  for (int l = 0; l < 3; ++l) {
    lin(hin, hlda, sg_wm[l] + 16, 80, nullptr, Rb, 64, 64, 64, false, false);
    static_msg_kernel<<<(n + 3) / 4, 256, 0, stream>>>(Rb, ea, sg_wm[l], sg_bm[l],
                                                       srcp, csr, rowptr, aggb, n);
    lin(aggb, 64, sg_wu[l], 64, sg_bu[l], hout[l], 320, 64, 64, true, false);
    hin = hout[l]; hlda = 320;
  }

  // dynamic layers: h1 -> g1(CAT+64); g1 -> g2(CAT+128)
  const float* din[2] = {CAT + 0, CAT + 64};
  float* doutp[2] = {CAT + 64, CAT + 128};
  for (int l = 0; l < 2; ++l) {
    lin(din[l], 320, w1d[l], 64, dg_b1[l], Pb, 128, 64, 128, false, false);
    lin(din[l], 320, dg_w1[l] + 64, 128, nullptr, Qb, 128, 64, 128, false, false);
    dyn_conv_kernel<<<(n + 3) / 4, 256, 0, stream>>>(Pb, Qb, dg_w2[l], dg_b2[l],
                                                     knnb, doutp[l], 320, n);
  }

  // fusion
  lin(CAT, 320, f1_w, 320, f1_b, fu1, 64, 320, 64, true,  false);
  lin(CAT, 320, f2_w + 64, 384, f2_b, out, 64, 320, 64, false, false);
  lin(fu1, 64, f2_w, 384, nullptr, out, 64, 64, 64, false, true);
}

// Round 3
// 654.023 us; speedup vs baseline: 1.6960x; 1.0480x over previous
//
#include <hip/hip_runtime.h>

#define INF_F __builtin_inff()

// ---------------------------------------------------------------------------
// kNN, threshold-scan with register-chunk init + rare LDS-atomic append.
// One wave per target, 4 waves/block. Key = (dist_bits<<32)|j  (u64 ascending
// == (dist, index) lexicographic == reference top_k order; dist >= 0).
// Exactness: tau is always the exact 16th-smallest key seen so far; a key
// discarded at time t has key >= tau_t >= tau_final, and keys are unique, so
// no discarded key can belong to the final top-16.
// Distance arithmetic matches the reference bit-for-bit: contract off,
// separately rounded squares, sequential sum.
// ---------------------------------------------------------------------------
__device__ __forceinline__ unsigned long long
knn_refine_regs(unsigned long long v[5], int lane,
                unsigned long long* __restrict__ B,
                unsigned long long& topsave)
{
  unsigned long long tau = ~0ull;
#pragma unroll
  for (int r = 0; r < 16; ++r) {
    // lane-local min of 5 keys
    unsigned long long m = v[0]; int s = 0;
#pragma unroll
    for (int t = 1; t < 5; ++t) if (v[t] < m) { m = v[t]; s = t; }
    // wave butterfly min (keys unique -> exactly one owning lane)
    unsigned long long mm = m;
#pragma unroll
    for (int off = 32; off >= 1; off >>= 1) {
      const unsigned long long o = __shfl_xor(mm, off, 64);
      if (o < mm) mm = o;
    }
    const bool killer = (m == mm);
#pragma unroll
    for (int t = 0; t < 5; ++t) if (killer && s == t) v[t] = ~0ull;
    if (lane == r) topsave = mm;
    tau = mm;            // after round 15: exact 16th-smallest
  }
  if (lane < 16) B[lane] = topsave;
  return tau;
}

__global__ __launch_bounds__(256) void knn_kernel(const float* __restrict__ loc,
                                                  int* __restrict__ knn, int n)
{
#pragma clang fp contract(off)
  constexpr int CAP = 320;    // 16 kept + worst-case 256/iter + TRIG slack
  constexpr int TRIG = 64;
  __shared__ unsigned long long Bs[4][CAP];
  volatile __shared__ int cnts[4];
  const int wave = threadIdx.x >> 6, lane = threadIdx.x & 63;
  const int i = blockIdx.x * 4 + wave;
  if (i >= n) return;
  unsigned long long* B = Bs[wave];

  const float tx = loc[(size_t)i*4+0], ty = loc[(size_t)i*4+1];
  const float tz = loc[(size_t)i*4+2], tw = loc[(size_t)i*4+3];

  auto dist_key = [&](int j) -> unsigned long long {
    if (j >= n || j == i) return ~0ull;
    const float4 p = *(const float4*)(loc + (size_t)j*4);
    const float a0 = p.x - tx, a1 = p.y - ty, a2 = p.z - tz, a3 = p.w - tw;
    const float s0 = a0*a0, s1 = a1*a1, s2 = a2*a2, s3 = a3*a3;
    const float d = ((s0 + s1) + s2) + s3;
    return ((unsigned long long)__float_as_uint(d) << 32) | (unsigned)j;
  };

  // init: first 256 candidates straight from registers (no appends)
  unsigned long long v[5];
#pragma unroll
  for (int t = 0; t < 4; ++t) v[t] = dist_key(lane + 64*t);
  v[4] = ~0ull;
  unsigned long long topsave = ~0ull;
  unsigned long long tau = knn_refine_regs(v, lane, B, topsave);
  if (lane == 0) cnts[wave] = 16;

  for (int j0 = 256; j0 < n; j0 += 256) {
    const unsigned long long k0 = dist_key(j0 + lane);
    const unsigned long long k1 = dist_key(j0 + 64 + lane);
    const unsigned long long k2 = dist_key(j0 + 128 + lane);
    const unsigned long long k3 = dist_key(j0 + 192 + lane);
    if (k0 < tau) { const int p = atomicAdd((int*)&cnts[wave], 1); B[p] = k0; }
    if (k1 < tau) { const int p = atomicAdd((int*)&cnts[wave], 1); B[p] = k1; }
    if (k2 < tau) { const int p = atomicAdd((int*)&cnts[wave], 1); B[p] = k2; }
    if (k3 < tau) { const int p = atomicAdd((int*)&cnts[wave], 1); B[p] = k3; }
    const int c = cnts[wave];           // same-wave LDS ops are in-order
    if (c > TRIG) {
#pragma unroll
      for (int t = 0; t < 5; ++t) {
        const int idx = lane + 64*t;
        v[t] = (idx < c) ? B[idx] : ~0ull;
      }
      tau = knn_refine_regs(v, lane, B, topsave);
      if (lane == 0) cnts[wave] = 16;
    }
  }
  const int c = cnts[wave];
  if (c > 16) {
#pragma unroll
    for (int t = 0; t < 5; ++t) {
      const int idx = lane + 64*t;
      v[t] = (idx < c) ? B[idx] : ~0ull;
    }
    (void)knn_refine_regs(v, lane, B, topsave);
  }
  if (lane < 16) knn[(size_t)i*16 + lane] = (int)(topsave & 0xFFFFFFFFull);
}

// ---------------------------------------------------------------------------
// Pack dyn-layer weights: Wpq[256][64] = [w1a - w1b ; w1b], bpq = [b1 ; 0].
// P||Q = h @ Wpq^T + bpq, then t_e = relu(P[i] + Q[j]).
// ---------------------------------------------------------------------------
__global__ __launch_bounds__(256) void pack_kernel(const float* __restrict__ w1,
                                                   const float* __restrict__ b1,
                                                   float* __restrict__ wpq,
                                                   float* __restrict__ bpq)
{
  const int idx = blockIdx.x * 256 + threadIdx.x;
  if (idx < 128 * 64) {
    const int o = idx >> 6, i = idx & 63;
    const float a = w1[o*128 + i], b = w1[o*128 + 64 + i];
    wpq[idx] = a - b;               // P rows 0..127
    wpq[128*64 + idx] = b;          // Q rows 128..255
  }
  if (idx < 128) { bpq[idx] = b1[idx]; bpq[128 + idx] = 0.f; }
}

// ---------------------------------------------------------------------------
// Generic fp32 linear: C[M][cols] = act(A[M][K] @ W[cols][K]^T + bias)
// block = 256 threads (4 waves x 8 rows), tile 32 rows x 64 cols, K-step 64.
// W staged float4-transposed [Kgroup][channel] -> conflict-free b128 reads.
// ---------------------------------------------------------------------------
template<bool RELU, bool ACC>
__global__ __launch_bounds__(256) void linear_kernel(
    const float* __restrict__ A, int lda,
    const float* __restrict__ W, int ldw,
    const float* __restrict__ bias,
    float* __restrict__ C, int ldc, int M, int K)
{
  __shared__ float As[32 * 64];
  __shared__ float Ws[16 * 64 * 4];   // [g][c] float4, g = K/4 group
  const int m0 = blockIdx.x * 32;
  const int c0 = blockIdx.y * 64;
  const int tid = threadIdx.x;
  const int wave = tid >> 6, lane = tid & 63;
  const int c = c0 + lane;

  float acc[8];
#pragma unroll
  for (int t = 0; t < 8; ++t) acc[t] = 0.f;

  for (int kt = 0; kt < K; kt += 64) {
    // stage A tile [32][64] (coalesced)
    {
      int idx = tid;
#pragma unroll
      for (int itr = 0; itr < 2; ++itr, idx += 256) {
        const int row = idx >> 4, col4 = idx & 15;
        const int gr = m0 + row;
        float4 v = make_float4(0.f, 0.f, 0.f, 0.f);
        if (gr < M) v = *(const float4*)(A + (size_t)gr*lda + kt + col4*4);
        *(float4*)(As + row*64 + col4*4) = v;
      }
      // stage W tile f4-transposed: slot idx = g*64 + ch
      idx = tid;
#pragma unroll
      for (int itr = 0; itr < 4; ++itr, idx += 256) {
        const int ch = idx & 63, g = idx >> 6;
        const float4 v = *(const float4*)(W + (size_t)(c0 + ch)*ldw + kt + g*4);
        *(float4*)(Ws + idx*4) = v;
      }
    }
    __syncthreads();
    const float* ar = As + wave*8*64;
    for (int g = 0; g < 16; ++g) {
      const float4 w = *(const float4*)(Ws + (g*64 + lane)*4);  // conflict-free
#pragma unroll
      for (int t = 0; t < 8; ++t) {
        const float4 a = *(const float4*)(ar + t*64 + g*4);     // broadcast
        acc[t] = fmaf(w.x, a.x, fmaf(w.y, a.y, fmaf(w.z, a.z, fmaf(w.w, a.w, acc[t]))));
      }
    }
    __syncthreads();
  }

  const float b = bias ? bias[c] : 0.f;
#pragma unroll
  for (int t = 0; t < 8; ++t) {
    const int gr = m0 + wave*8 + t;
    if (gr < M) {
      float v = acc[t] + b;
      if (RELU) v = fmaxf(v, 0.f);
      float* cp = C + (size_t)gr*ldc + c;
      if (ACC) v += *cp;
      *cp = v;
    }
  }
}

// ---------------------------------------------------------------------------
// Static conv, edge-parallel with atomicMax (float bits, values >= 0, agg
// pre-zeroed in-graph). Exact & order-independent => deterministic.
// wave handles 8 edges, lane = output channel.
// ---------------------------------------------------------------------------
__global__ __launch_bounds__(256) void static_edge_kernel(
    const float* __restrict__ R, const float* __restrict__ ea,
    const float* __restrict__ wm, const float* __restrict__ bm,
    const int* __restrict__ srcs, const int* __restrict__ dsts,
    float* __restrict__ agg, int E)
{
  __shared__ float wma[64][17];   // cols 0..15 of wm, padded (stride 17: free)
  __shared__ float bms[64];
  for (int idx = threadIdx.x; idx < 1024; idx += 256) {
    const int r = idx >> 4, cc = idx & 15;
    wma[r][cc] = wm[r*80 + cc];
  }
  if (threadIdx.x < 64) bms[threadIdx.x] = bm[threadIdx.x];
  __syncthreads();
  const int wave = threadIdx.x >> 6, lane = threadIdx.x & 63;
  const int e0 = (blockIdx.x * 4 + wave) * 8;
  const float* wr = wma[lane];
  const float bb = bms[lane];
#pragma unroll 2
  for (int t = 0; t < 8; ++t) {
    const int e = e0 + t;
    if (e >= E) break;
    const int s = srcs[e], d = dsts[e];
    float acc = bb + R[(size_t)s*64 + lane] - R[(size_t)d*64 + lane];
    const float4* e4 = (const float4*)(ea + (size_t)e*16);
    const float4 q0 = e4[0], q1 = e4[1], q2 = e4[2], q3 = e4[3];
    acc = fmaf(q0.x, wr[0],  acc); acc = fmaf(q0.y, wr[1],  acc);
    acc = fmaf(q0.z, wr[2],  acc); acc = fmaf(q0.w, wr[3],  acc);
    acc = fmaf(q1.x, wr[4],  acc); acc = fmaf(q1.y, wr[5],  acc);
    acc = fmaf(q1.z, wr[6],  acc); acc = fmaf(q1.w, wr[7],  acc);
    acc = fmaf(q2.x, wr[8],  acc); acc = fmaf(q2.y, wr[9],  acc);
    acc = fmaf(q2.z, wr[10], acc); acc = fmaf(q2.w, wr[11], acc);
    acc = fmaf(q3.x, wr[12], acc); acc = fmaf(q3.y, wr[13], acc);
    acc = fmaf(q3.z, wr[14], acc); acc = fmaf(q3.w, wr[15], acc);
    const float m = fmaxf(acc, 0.f);
    atomicMax((int*)(agg + (size_t)d*64) + lane, __float_as_int(m));
  }
}

// ---------------------------------------------------------------------------
// Dynamic conv: per target i, 17 neighbors (16 kNN + self).
// t_e = relu(P[i] + Q[j]); out[i][c] = relu(max_e (t_e . W2[c]) + b2[c]).
// W2 staged f4-transposed [g][c] -> conflict-free b128; T reads broadcast.
// ---------------------------------------------------------------------------
template<int NB>
__device__ __forceinline__ float dyn_block(
    int i, int nb0, const int* __restrict__ knn,
    const float* __restrict__ PQ,
    const float* __restrict__ w2s, float* __restrict__ Tw,
    int lane, float vmax)
{
  for (int idx = lane; idx < NB * 32; idx += 64) {
    const int off = idx << 2;
    const int nb = off >> 7, kk = off & 127;
    const int nbg = nb0 + nb;
    const int j = (nbg < 16) ? knn[(size_t)i*16 + nbg] : i;
    const float4 p = *(const float4*)(PQ + (size_t)i*256 + kk);
    const float4 q = *(const float4*)(PQ + (size_t)j*256 + 128 + kk);
    float4 t;
    t.x = fmaxf(p.x + q.x, 0.f); t.y = fmaxf(p.y + q.y, 0.f);
    t.z = fmaxf(p.z + q.z, 0.f); t.w = fmaxf(p.w + q.w, 0.f);
    *(float4*)(Tw + off) = t;
  }
  __syncthreads();
  float acc[NB];
#pragma unroll
  for (int t = 0; t < NB; ++t) acc[t] = 0.f;
  for (int g = 0; g < 32; ++g) {
    const float4 w = *(const float4*)(w2s + (g*64 + lane)*4);   // conflict-free
#pragma unroll
    for (int t = 0; t < NB; ++t) {
      const float4 tv = *(const float4*)(Tw + t*128 + g*4);     // broadcast
      acc[t] = fmaf(w.x, tv.x, fmaf(w.y, tv.y, fmaf(w.z, tv.z, fmaf(w.w, tv.w, acc[t]))));
    }
  }
#pragma unroll
  for (int t = 0; t < NB; ++t) vmax = fmaxf(vmax, acc[t]);
  return vmax;
}

__global__ __launch_bounds__(256) void dyn_conv_kernel(
    const float* __restrict__ PQ,
    const float* __restrict__ W2, const float* __restrict__ b2,
    const int* __restrict__ knn, float* __restrict__ out, int ldo, int n)
{
  __shared__ float w2s[32 * 64 * 4];   // [g][c] float4 of W2 rows
  __shared__ float T[4][1152];         // per-wave [9][128]
  for (int idx = threadIdx.x; idx < 2048; idx += 256) {
    const int ch = idx & 63, g = idx >> 6;
    *(float4*)(w2s + idx*4) = *(const float4*)(W2 + (size_t)ch*128 + g*4);
  }
  __syncthreads();
  const int wave = threadIdx.x >> 6, lane = threadIdx.x & 63;
  const int i = blockIdx.x * 4 + wave;
  float vmax = -INF_F;
  vmax = dyn_block<9>(i, 0, knn, PQ, w2s, T[wave], lane, vmax);
  vmax = dyn_block<8>(i, 9, knn, PQ, w2s, T[wave], lane, vmax);
  if (i < n) out[(size_t)i*ldo + lane] = fmaxf(vmax + b2[lane], 0.f);
}

// ---------------------------------------------------------------------------
// Host orchestration
// ---------------------------------------------------------------------------
extern "C" void kernel_launch(void* const* d_in, const int* in_sizes, int n_in,
                              void* d_out, int out_size, void* d_ws, size_t ws_size,
                              hipStream_t stream)
{
  const float* x   = (const float*)d_in[0];
  const int*   ei  = (const int*)d_in[1];
  const float* ea  = (const float*)d_in[2];
  const float* loc = (const float*)d_in[3];
  const float* sg_wm[3] = {(const float*)d_in[5],  (const float*)d_in[9],  (const float*)d_in[13]};
  const float* sg_bm[3] = {(const float*)d_in[6],  (const float*)d_in[10], (const float*)d_in[14]};
  const float* sg_wu[3] = {(const float*)d_in[7],  (const float*)d_in[11], (const float*)d_in[15]};
  const float* sg_bu[3] = {(const float*)d_in[8],  (const float*)d_in[12], (const float*)d_in[16]};
  const float* dg_w1[2] = {(const float*)d_in[17], (const float*)d_in[21]};
  const float* dg_b1[2] = {(const float*)d_in[18], (const float*)d_in[22]};
  const float* dg_w2[2] = {(const float*)d_in[19], (const float*)d_in[23]};
  const float* dg_b2[2] = {(const float*)d_in[20], (const float*)d_in[24]};
  const float* f1_w = (const float*)d_in[25];
  const float* f1_b = (const float*)d_in[26];
  const float* f2_w = (const float*)d_in[27];
  const float* f2_b = (const float*)d_in[28];
  float* out = (float*)d_out;

  const int n    = in_sizes[0] / 64;
  const int Etot = in_sizes[1] / 2;
  const int* srcp = ei;
  const int* dstp = ei + Etot;

  char* basep = (char*)d_ws;
  size_t cur = 0;
  auto alloc = [&](size_t bytes) -> void* {
    void* p = basep + cur;
    cur = (cur + bytes + 255) & ~(size_t)255;
    return p;
  };
  float* CAT  = (float*)alloc((size_t)n * 320 * 4);
  float* Rb   = (float*)alloc((size_t)n * 64 * 4);
  float* PQb  = (float*)alloc((size_t)n * 256 * 4);
  float* agg3 = (float*)alloc((size_t)3 * n * 64 * 4);   // one memset covers all
  float* fu1  = (float*)alloc((size_t)n * 64 * 4);
  float* wpq[2];
  float* bpq[2];
  wpq[0] = (float*)alloc(256 * 64 * 4);  bpq[0] = (float*)alloc(256 * 4);
  wpq[1] = (float*)alloc(256 * 64 * 4);  bpq[1] = (float*)alloc(256 * 4);
  int* knnb   = (int*)alloc((size_t)n * 16 * 4);
  (void)ws_size; (void)n_in; (void)out_size;

  hipMemsetAsync(agg3, 0, (size_t)3 * n * 64 * 4, stream);
  knn_kernel<<<(n + 3) / 4, 256, 0, stream>>>(loc, knnb, n);
  pack_kernel<<<32, 256, 0, stream>>>(dg_w1[0], dg_b1[0], wpq[0], bpq[0]);
  pack_kernel<<<32, 256, 0, stream>>>(dg_w1[1], dg_b1[1], wpq[1], bpq[1]);

  const int mb = (n + 31) / 32;
  auto lin = [&](const float* A, int lda, const float* W, int ldw, const float* bias,
                 float* C, int ldc, int K, int ncols, bool relu, bool accum) {
    dim3 grid(mb, ncols / 64);
    if (relu)       linear_kernel<true,  false><<<grid, 256, 0, stream>>>(A, lda, W, ldw, bias, C, ldc, n, K);
    else if (accum) linear_kernel<false, true ><<<grid, 256, 0, stream>>>(A, lda, W, ldw, bias, C, ldc, n, K);
    else            linear_kernel<false, false><<<grid, 256, 0, stream>>>(A, lda, W, ldw, bias, C, ldc, n, K);
  };

  const int eb = (Etot + 31) / 32;   // 4 waves x 8 edges per block

  // static layers: x -> h1(CAT+0) -> h2(CAT+192) -> h3(CAT+256)
  const float* hin = x; int hlda = 64;
  float* hout[3] = {CAT + 0, CAT + 192, CAT + 256};
  for (int l = 0; l < 3; ++l) {
    float* agg = agg3 + (size_t)l * n * 64;
    lin(hin, hlda, sg_wm[l] + 16, 80, nullptr, Rb, 64, 64, 64, false, false);
    static_edge_kernel<<<eb, 256, 0, stream>>>(Rb, ea, sg_wm[l], sg_bm[l],
                                               srcp, dstp, agg, Etot);
    lin(agg, 64, sg_wu[l], 64, sg_bu[l], hout[l], 320, 64, 64, true, false);
    hin = hout[l]; hlda = 320;
  }

  // dynamic layers: h1 -> g1(CAT+64); g1 -> g2(CAT+128)
  const float* din[2] = {CAT + 0, CAT + 64};
  float* doutp[2] = {CAT + 64, CAT + 128};
  for (int l = 0; l < 2; ++l) {
    lin(din[l], 320, wpq[l], 64, bpq[l], PQb, 256, 64, 256, false, false);
    dyn_conv_kernel<<<(n + 3) / 4, 256, 0, stream>>>(PQb, dg_w2[l], dg_b2[l],
                                                     knnb, doutp[l], 320, n);
  }

  // fusion
  lin(CAT, 320, f1_w, 320, f1_b, fu1, 64, 320, 64, true,  false);
  lin(CAT, 320, f2_w + 64, 384, f2_b, out, 64, 320, 64, false, false);
  lin(fu1, 64, f2_w, 384, nullptr, out, 64, 64, 64, false, true);
}